// Round 8
// baseline (196.032 us; speedup 1.0000x reference)
//
#include <hip/hip_runtime.h>
#include <stdint.h>

#define B_    16
#define FIN   256
#define FOUT  256
#define FH2   256
#define NMIX  8
#define LAT   512
#define HW    4096
#define MT    64

typedef short bf16x8 __attribute__((ext_vector_type(8)));
typedef float f32x4  __attribute__((ext_vector_type(4)));
typedef float f32x16 __attribute__((ext_vector_type(16)));

// workspace layout (bytes) -- sizes unchanged; fragment ORDER inside w_* changed
// to the 32x32x16 packing (see k_weights).
#define WS_MIX    0           // [16][8] f32
#define WS_BIAS   1024        // [4][16][256] f32 : in, mid, out, short
#define WS_WIN    131072      // [16][65536] bf16, fragment-packed (32x32x16)
#define WS_WMID   2228224     // [16][131072] bf16, fragment-packed + sin/cos ileave
#define WS_WOUT   6422528     // [16][131072] bf16
#define WS_WSHORT 10616832    // [16][65536] bf16

// RNE f32->bf16, bit-twiddle (PROVEN bits; round-6 lesson: v_cvt_pk_bf16_f32 is
// NOT bit-identical -- do not substitute).
__device__ __forceinline__ uint16_t f2bf(float f) {
  uint32_t u = __builtin_bit_cast(uint32_t, f);
  u += 0x7fffu + ((u >> 16) & 1u);
  return (uint16_t)(u >> 16);
}
__device__ __forceinline__ uint32_t pack2(float lo, float hi) {
  return (uint32_t)f2bf(lo) | ((uint32_t)f2bf(hi) << 16);
}

// 32x32x16 bf16 MFMA. Layouts (gfx950):
//   A (32 rows x 16 k): row = lane&31, k = (lane>>5)*8 + j   (8 bf16/lane)
//   B (16 k x 32 cols): col = lane&31, k = (lane>>5)*8 + j
//   C/D: col = lane&31, row = (reg&3) + 8*(reg>>2) + 4*(lane>>5)  [m74/m101]
#define MFMA32(a, b, c) __builtin_amdgcn_mfma_f32_32x32x16_bf16(a, b, c, 0, 0, 0)

// ---------------- kernel A: mix + biases (one block per sample) ----------------
__global__ void k_mix_bias(const float* __restrict__ lat,
                           const float* __restrict__ w_dyna,
                           const float* __restrict__ b_dyna,
                           const float* __restrict__ b_in_mix,
                           const float* __restrict__ b_mid_mix,
                           const float* __restrict__ b_out_mix,
                           const float* __restrict__ b_short_mix,
                           float* __restrict__ ws_mix,
                           float* __restrict__ ws_bias) {
  __shared__ float smix[NMIX];
  const int t = threadIdx.x;
  const int lane = t & 63, wv = t >> 6;
  const int b = blockIdx.x;
#pragma unroll
  for (int d2 = 0; d2 < 2; d2++) {
    int m = wv * 2 + d2;
    float s = 0.f;
#pragma unroll
    for (int j = 0; j < 8; j++)
      s += lat[b * LAT + j * 64 + lane] * w_dyna[m * LAT + j * 64 + lane];
#pragma unroll
    for (int off = 32; off; off >>= 1) s += __shfl_xor(s, off);
    if (lane == 0) {
      float v = s + b_dyna[m];
      ws_mix[b * NMIX + m] = v;
      smix[m] = v;
    }
  }
  __syncthreads();
  const float* banks[4] = {b_in_mix, b_mid_mix, b_out_mix, b_short_mix};
  for (int pos = t; pos < 1024; pos += 256) {
    int bank = pos >> 8, ch = pos & 255;
    const float* bp = banks[bank];
    float a = 0.f;
#pragma unroll
    for (int m = 0; m < NMIX; m++) a += smix[m] * bp[m * 256 + ch];
    ws_bias[(bank * B_ + b) * 256 + ch] = a;
  }
}

// ---------------- kernel B: mixed per-sample bf16 weights, FRAGMENT-PACKED ----
// 32x32x16 packing. Packed element order per sample per matrix:
//   e = ((wv*KT + kt)*2 + or)*512 + lane*8 + j
// holding W[row = wv*64 + or*32 + (lane&31)][k = kt*16 + (lane>>5)*8 + j]
// For w_mid/w_out, k is the PERMUTED k' (sin/cos interleave): orig col
// i = (k'>>1) + ((k'&1)<<8). 8-elem-per-thread vectorized as in rounds 3-7.
__global__ void k_weights(const float* __restrict__ k_in_mix,
                          const float* __restrict__ k_mid_mix,
                          const float* __restrict__ k_out_mix,
                          const float* __restrict__ k_short_mix,
                          const float* __restrict__ ws_mix,
                          uint16_t* __restrict__ w_in,
                          uint16_t* __restrict__ w_mid,
                          uint16_t* __restrict__ w_out,
                          uint16_t* __restrict__ w_short) {
  __shared__ float smix[B_ * NMIX];
  const int t = threadIdx.x;
  if (t < B_ * NMIX) smix[t] = ws_mix[t];
  __syncthreads();
  const int e8 = (blockIdx.x * 256 + t) * 8;  // 8-aligned packed position
  const float* srcA;
  uint16_t* dst;
  int sstride, dstride;
  bool ileave;  // block-uniform
  if (e8 < 65536) {                       // w_in, KT=16
    int e = e8;
    int lane = (e >> 3) & 63, orr = (e >> 9) & 1, kt = (e >> 10) & 15, wv = e >> 14;
    int row = wv * 64 + orr * 32 + (lane & 31);
    int k0 = kt * 16 + (lane >> 5) * 8;
    srcA = k_in_mix + row * 256 + k0; sstride = 65536; ileave = false;
    dst = w_in + e;                   dstride = 65536;
  } else if (e8 < 196608) {               // w_mid, KT=32, sin/cos interleave
    int e = e8 - 65536;
    int lane = (e >> 3) & 63, orr = (e >> 9) & 1, kt = (e >> 10) & 31, wv = e >> 15;
    int row = wv * 64 + orr * 32 + (lane & 31);
    int kp0 = kt * 16 + (lane >> 5) * 8;       // 8-aligned -> i0 = kp0/2, 4-aligned
    srcA = k_mid_mix + row * 512 + (kp0 >> 1); sstride = 131072; ileave = true;
    dst = w_mid + e;                           dstride = 131072;
  } else if (e8 < 327680) {               // w_out, KT=32, interleave
    int e = e8 - 196608;
    int lane = (e >> 3) & 63, orr = (e >> 9) & 1, kt = (e >> 10) & 31, wv = e >> 15;
    int row = wv * 64 + orr * 32 + (lane & 31);
    int kp0 = kt * 16 + (lane >> 5) * 8;
    srcA = k_out_mix + row * 512 + (kp0 >> 1); sstride = 131072; ileave = true;
    dst = w_out + e;                           dstride = 131072;
  } else {                                // w_short, KT=16
    int e = e8 - 327680;
    int lane = (e >> 3) & 63, orr = (e >> 9) & 1, kt = (e >> 10) & 15, wv = e >> 14;
    int row = wv * 64 + orr * 32 + (lane & 31);
    int k0 = kt * 16 + (lane >> 5) * 8;
    srcA = k_short_mix + row * 256 + k0; sstride = 65536; ileave = false;
    dst = w_short + e;                   dstride = 65536;
  }
  // srcB offset: non-interleaved -> +4 (elements 4..7); interleaved -> +256 (cos half)
  const int boff = ileave ? 256 : 4;
  float4 va[NMIX], vb[NMIX];
#pragma unroll
  for (int m = 0; m < NMIX; m++) {
    va[m] = *(const float4*)(srcA + m * sstride);
    vb[m] = *(const float4*)(srcA + m * sstride + boff);
  }
  for (int b = 0; b < B_; b++) {
    float4 ra = make_float4(0.f, 0.f, 0.f, 0.f), rb = ra;
#pragma unroll
    for (int m = 0; m < NMIX; m++) {
      const float s = smix[b * NMIX + m];
      ra.x += s * va[m].x; ra.y += s * va[m].y; ra.z += s * va[m].z; ra.w += s * va[m].w;
      rb.x += s * vb[m].x; rb.y += s * vb[m].y; rb.z += s * vb[m].z; rb.w += s * vb[m].w;
    }
    int4 pkt;
    if (ileave) {  // out order: a0,b0,a1,b1,a2,b2,a3,b3  (sin/cos interleave)
      pkt = make_int4((int)pack2(ra.x, rb.x), (int)pack2(ra.y, rb.y),
                      (int)pack2(ra.z, rb.z), (int)pack2(ra.w, rb.w));
    } else {       // out order: a0,a1,a2,a3,b0,b1,b2,b3
      pkt = make_int4((int)pack2(ra.x, ra.y), (int)pack2(ra.z, ra.w),
                      (int)pack2(rb.x, rb.y), (int)pack2(rb.z, rb.w));
    }
    *(int4*)(dst + (size_t)b * dstride) = pkt;
  }
}

// ---------------- main fused kernel (v8: 32x32x16 MFMA) ----
// vs v7 (74 us): MFMA shape 16x16x32 -> 32x32x16. Pipe rate 3377 -> 4060
// FLOP/cyc/CU (-17% on the dominant pipe); MFMA instruction count halves
// (768 -> 384/wave -> half the issue pressure); weight-fragment buffers halve
// (~30 regs of new slack). Everything else (streaming, barriers, f2bf bits,
// LDS swizzles) preserved.
// Per wave: 64 och x 64 pos = 2(or) x 2(pc) tiles of 32x32; acc = 128 f32.
__launch_bounds__(256, 2)
__global__ void k_main(const float* __restrict__ x,
                       const float* __restrict__ ws_bias,
                       const uint16_t* __restrict__ w_in,
                       const uint16_t* __restrict__ w_mid,
                       const uint16_t* __restrict__ w_out,
                       const uint16_t* __restrict__ w_short,
                       float* __restrict__ out) {
  __shared__ int4 smem4[65536 / 16];
  char* lds = (char*)smem4;
  char* Xs = lds;            // 32768 B: [64 pos][256 ch] bf16, chunk-xor swz
  char* H1 = lds;            // 65536 B: [64 pos][512 k'] bf16 (after phase A)

  const int t = threadIdx.x;
  const int lane = t & 63;
  const int wv = t >> 6;     // 0..3
  const int l31 = lane & 31;
  const int ks = lane >> 5;  // 0..1 (k-subgroup)
  const int b = blockIdx.x & 15;
  const int p0 = (blockIdx.x >> 4) * MT;

  const float* xb = x + (size_t)b * FIN * HW + p0;
  const int xpos = t & 63;   // position this thread stages

  // ---- stage FULL X tile: 64 scalar loads/thread, one burst, one drain ----
  {
    float xr[8][8];
#pragma unroll
    for (int u = 0; u < 8; u++) {
      const int cg = wv * 8 + u;  // 8-channel group 0..31
#pragma unroll
      for (int e = 0; e < 8; e++)
        xr[u][e] = xb[(size_t)(cg * 8 + e) * HW + xpos];
    }
#pragma unroll
    for (int u = 0; u < 8; u++) {
      const int cg = wv * 8 + u;
      *(int4*)(Xs + xpos * 512 + ((cg ^ (xpos & 7)) * 16)) = make_int4(
          (int)pack2(xr[u][0], xr[u][1]), (int)pack2(xr[u][2], xr[u][3]),
          (int)pack2(xr[u][4], xr[u][5]), (int)pack2(xr[u][6], xr[u][7]));
    }
  }

  // ---- phase A accumulator init: h = b_in, s = b_short ----
  // element r of acc[or][pc]: och = wv*64 + or*32 + (r&3) + 8*(r>>2) + 4*ks
  f32x16 acc_h[2][2], acc_s[2][2];
#pragma unroll
  for (int orr = 0; orr < 2; orr++) {
    float4 bh[4], bs[4];
#pragma unroll
    for (int g = 0; g < 4; g++) {
      const int o0 = wv * 64 + orr * 32 + g * 8 + 4 * ks;
      bh[g] = *(const float4*)&ws_bias[(0 * B_ + b) * 256 + o0];
      bs[g] = *(const float4*)&ws_bias[(3 * B_ + b) * 256 + o0];
    }
#pragma unroll
    for (int pc = 0; pc < 2; pc++) {
#pragma unroll
      for (int g = 0; g < 4; g++) {
        acc_h[orr][pc][4 * g + 0] = bh[g].x; acc_h[orr][pc][4 * g + 1] = bh[g].y;
        acc_h[orr][pc][4 * g + 2] = bh[g].z; acc_h[orr][pc][4 * g + 3] = bh[g].w;
        acc_s[orr][pc][4 * g + 0] = bs[g].x; acc_s[orr][pc][4 * g + 1] = bs[g].y;
        acc_s[orr][pc][4 * g + 2] = bs[g].z; acc_s[orr][pc][4 * g + 3] = bs[g].w;
      }
    }
  }

  // phase-A weight prefetch: kt=0 -> buf0, kt=1 -> buf1 (kt stride 1024 elems)
  const uint16_t* Wi = w_in + (size_t)b * 65536 + wv * 16384 + lane * 8;
  const uint16_t* Ws = w_short + (size_t)b * 65536 + wv * 16384 + lane * 8;
  bf16x8 ai[2][2], asf[2][2];
#pragma unroll
  for (int orr = 0; orr < 2; orr++) {
    ai[0][orr] = *(const bf16x8*)(Wi + 0 * 1024 + orr * 512);
    asf[0][orr] = *(const bf16x8*)(Ws + 0 * 1024 + orr * 512);
    ai[1][orr] = *(const bf16x8*)(Wi + 1 * 1024 + orr * 512);
    asf[1][orr] = *(const bf16x8*)(Ws + 1 * 1024 + orr * 512);
  }
  __syncthreads();  // bar1: X staged

  // ---- phase A: 16 kt-steps of K=16; 8 MFMA/kt; dist-2 weight refill ----
#pragma unroll
  for (int kt = 0; kt < 16; kt++) {
    bf16x8 bf[2];
#pragma unroll
    for (int pc = 0; pc < 2; pc++) {
      const int pos = pc * 32 + l31;
      const int cg = kt * 2 + ks;
      bf[pc] = *(const bf16x8*)(Xs + pos * 512 + ((cg ^ (pos & 7)) * 16));
    }
    __builtin_amdgcn_s_setprio(1);
#pragma unroll
    for (int orr = 0; orr < 2; orr++) {
#pragma unroll
      for (int pc = 0; pc < 2; pc++) {
        acc_h[orr][pc] = MFMA32(ai[kt & 1][orr], bf[pc], acc_h[orr][pc]);
        acc_s[orr][pc] = MFMA32(asf[kt & 1][orr], bf[pc], acc_s[orr][pc]);
      }
    }
    __builtin_amdgcn_s_setprio(0);
    if (kt < 14) {  // refill just-consumed buffer with kt+2
#pragma unroll
      for (int orr = 0; orr < 2; orr++) {
        ai[kt & 1][orr] = *(const bf16x8*)(Wi + (kt + 2) * 1024 + orr * 512);
        asf[kt & 1][orr] = *(const bf16x8*)(Ws + (kt + 2) * 1024 + orr * 512);
      }
    }
  }
  __syncthreads();  // bar2: all X reads done before H1 overwrites

  // ---- complex_wave(h1) -> H1: k' = 2*och + {0:sin,1:cos} ----
  // int4 per (or,pc,g) holds k'-group ctile16 = wv*16 + or*8 + g*2 + ks
#pragma unroll
  for (int orr = 0; orr < 2; orr++) {
#pragma unroll
    for (int pc = 0; pc < 2; pc++) {
      const int pos = pc * 32 + l31;
#pragma unroll
      for (int g = 0; g < 4; g++) {
        const int ct = wv * 16 + orr * 8 + g * 2 + ks;
        *(int4*)(H1 + pos * 1024 + ((ct ^ (pos & 7)) * 16)) = make_int4(
            (int)pack2(__sinf(acc_h[orr][pc][4 * g + 0]), __cosf(acc_h[orr][pc][4 * g + 0])),
            (int)pack2(__sinf(acc_h[orr][pc][4 * g + 1]), __cosf(acc_h[orr][pc][4 * g + 1])),
            (int)pack2(__sinf(acc_h[orr][pc][4 * g + 2]), __cosf(acc_h[orr][pc][4 * g + 2])),
            (int)pack2(__sinf(acc_h[orr][pc][4 * g + 3]), __cosf(acc_h[orr][pc][4 * g + 3])));
      }
    }
  }

  // phase-B prologue: bias init + 3 weight buffers (kt 0,1,2)
  const uint16_t* Wm = w_mid + (size_t)b * 131072 + wv * 32768 + lane * 8;
  bf16x8 am[3][2];
#pragma unroll
  for (int orr = 0; orr < 2; orr++) {
    am[0][orr] = *(const bf16x8*)(Wm + 0 * 1024 + orr * 512);
    am[1][orr] = *(const bf16x8*)(Wm + 1 * 1024 + orr * 512);
    am[2][orr] = *(const bf16x8*)(Wm + 2 * 1024 + orr * 512);
  }
  f32x16 acc2[2][2];
#pragma unroll
  for (int orr = 0; orr < 2; orr++) {
    float4 bm[4];
#pragma unroll
    for (int g = 0; g < 4; g++) {
      const int o0 = wv * 64 + orr * 32 + g * 8 + 4 * ks;
      bm[g] = *(const float4*)&ws_bias[(1 * B_ + b) * 256 + o0];
    }
#pragma unroll
    for (int pc = 0; pc < 2; pc++) {
#pragma unroll
      for (int g = 0; g < 4; g++) {
        acc2[orr][pc][4 * g + 0] = bm[g].x; acc2[orr][pc][4 * g + 1] = bm[g].y;
        acc2[orr][pc][4 * g + 2] = bm[g].z; acc2[orr][pc][4 * g + 3] = bm[g].w;
      }
    }
  }
  __syncthreads();  // bar3: H1 writes visible

  // ---- phase B: 32 kt-steps of K=16; ds ping-pong; dist-3 weight refill ----
  {
    bf16x8 bfP[2][2];
#pragma unroll
    for (int pc = 0; pc < 2; pc++) {
      const int pos = pc * 32 + l31;
      bfP[0][pc] = *(const bf16x8*)(H1 + pos * 1024 + ((ks ^ (pos & 7)) * 16));
    }
#pragma unroll
    for (int kt = 0; kt < 32; kt++) {
      if (kt < 31) {
#pragma unroll
        for (int pc = 0; pc < 2; pc++) {
          const int pos = pc * 32 + l31;
          const int cg = (kt + 1) * 2 + ks;
          bfP[(kt + 1) & 1][pc] =
              *(const bf16x8*)(H1 + pos * 1024 + ((cg ^ (pos & 7)) * 16));
        }
      }
      __builtin_amdgcn_s_setprio(1);
#pragma unroll
      for (int orr = 0; orr < 2; orr++)
#pragma unroll
        for (int pc = 0; pc < 2; pc++)
          acc2[orr][pc] = MFMA32(am[kt % 3][orr], bfP[kt & 1][pc], acc2[orr][pc]);
      __builtin_amdgcn_s_setprio(0);
      if (kt < 29) {
#pragma unroll
        for (int orr = 0; orr < 2; orr++)
          am[kt % 3][orr] = *(const bf16x8*)(Wm + (kt + 3) * 1024 + orr * 512);
      }
    }
  }
  __syncthreads();  // bar4: all H1 reads done before overwrite

  // ---- complex_wave(h2) -> H2 (overlays H1 region) ----
#pragma unroll
  for (int orr = 0; orr < 2; orr++) {
#pragma unroll
    for (int pc = 0; pc < 2; pc++) {
      const int pos = pc * 32 + l31;
#pragma unroll
      for (int g = 0; g < 4; g++) {
        const int ct = wv * 16 + orr * 8 + g * 2 + ks;
        *(int4*)(H1 + pos * 1024 + ((ct ^ (pos & 7)) * 16)) = make_int4(
            (int)pack2(__sinf(acc2[orr][pc][4 * g + 0]), __cosf(acc2[orr][pc][4 * g + 0])),
            (int)pack2(__sinf(acc2[orr][pc][4 * g + 1]), __cosf(acc2[orr][pc][4 * g + 1])),
            (int)pack2(__sinf(acc2[orr][pc][4 * g + 2]), __cosf(acc2[orr][pc][4 * g + 2])),
            (int)pack2(__sinf(acc2[orr][pc][4 * g + 3]), __cosf(acc2[orr][pc][4 * g + 3])));
      }
    }
  }

  // phase-C prologue: acc_s += b_out; 3 weight buffers
  const uint16_t* Wo = w_out + (size_t)b * 131072 + wv * 32768 + lane * 8;
  bf16x8 ao[3][2];
#pragma unroll
  for (int orr = 0; orr < 2; orr++) {
    ao[0][orr] = *(const bf16x8*)(Wo + 0 * 1024 + orr * 512);
    ao[1][orr] = *(const bf16x8*)(Wo + 1 * 1024 + orr * 512);
    ao[2][orr] = *(const bf16x8*)(Wo + 2 * 1024 + orr * 512);
  }
#pragma unroll
  for (int orr = 0; orr < 2; orr++) {
    float4 bo[4];
#pragma unroll
    for (int g = 0; g < 4; g++) {
      const int o0 = wv * 64 + orr * 32 + g * 8 + 4 * ks;
      bo[g] = *(const float4*)&ws_bias[(2 * B_ + b) * 256 + o0];
    }
#pragma unroll
    for (int pc = 0; pc < 2; pc++) {
#pragma unroll
      for (int g = 0; g < 4; g++) {
        acc_s[orr][pc][4 * g + 0] += bo[g].x; acc_s[orr][pc][4 * g + 1] += bo[g].y;
        acc_s[orr][pc][4 * g + 2] += bo[g].z; acc_s[orr][pc][4 * g + 3] += bo[g].w;
      }
    }
  }
  __syncthreads();  // bar5: H2 writes visible

  // ---- phase C: out = K_out(perm) @ H2c + b_out + short ----
  {
    bf16x8 bfP[2][2];
#pragma unroll
    for (int pc = 0; pc < 2; pc++) {
      const int pos = pc * 32 + l31;
      bfP[0][pc] = *(const bf16x8*)(H1 + pos * 1024 + ((ks ^ (pos & 7)) * 16));
    }
#pragma unroll
    for (int kt = 0; kt < 32; kt++) {
      if (kt < 31) {
#pragma unroll
        for (int pc = 0; pc < 2; pc++) {
          const int pos = pc * 32 + l31;
          const int cg = (kt + 1) * 2 + ks;
          bfP[(kt + 1) & 1][pc] =
              *(const bf16x8*)(H1 + pos * 1024 + ((cg ^ (pos & 7)) * 16));
        }
      }
      __builtin_amdgcn_s_setprio(1);
#pragma unroll
      for (int orr = 0; orr < 2; orr++)
#pragma unroll
        for (int pc = 0; pc < 2; pc++)
          acc_s[orr][pc] = MFMA32(ao[kt % 3][orr], bfP[kt & 1][pc], acc_s[orr][pc]);
      __builtin_amdgcn_s_setprio(0);
      if (kt < 29) {
#pragma unroll
        for (int orr = 0; orr < 2; orr++)
          ao[kt % 3][orr] = *(const bf16x8*)(Wo + (kt + 3) * 1024 + orr * 512);
      }
    }
  }

  // ---- store: och = wv*64 + or*32 + (r&3)+8*(r>>2)+4*ks, pos = pc*32+l31 ----
  {
    float* ob = out + (size_t)b * FOUT * HW + p0;
#pragma unroll
    for (int orr = 0; orr < 2; orr++) {
#pragma unroll
      for (int pc = 0; pc < 2; pc++) {
        const int pos = pc * 32 + l31;
#pragma unroll
        for (int g = 0; g < 4; g++) {
#pragma unroll
          for (int i = 0; i < 4; i++) {
            const int och = wv * 64 + orr * 32 + g * 8 + 4 * ks + i;
            ob[(size_t)och * HW + pos] = acc_s[orr][pc][4 * g + i];
          }
        }
      }
    }
  }
}

extern "C" void kernel_launch(void* const* d_in, const int* in_sizes, int n_in,
                              void* d_out, int out_size, void* d_ws, size_t ws_size,
                              hipStream_t stream) {
  const float* x           = (const float*)d_in[0];
  const float* lat         = (const float*)d_in[1];
  const float* k_in_mix    = (const float*)d_in[2];
  const float* k_mid_mix   = (const float*)d_in[3];
  const float* k_out_mix   = (const float*)d_in[4];
  const float* k_short_mix = (const float*)d_in[5];
  const float* b_in_mix    = (const float*)d_in[6];
  const float* b_mid_mix   = (const float*)d_in[7];
  const float* b_out_mix   = (const float*)d_in[8];
  const float* b_short_mix = (const float*)d_in[9];
  const float* w_dyna      = (const float*)d_in[10];
  const float* b_dyna      = (const float*)d_in[11];

  char* ws = (char*)d_ws;
  float*    ws_mix  = (float*)(ws + WS_MIX);
  float*    ws_bias = (float*)(ws + WS_BIAS);
  uint16_t* w_in    = (uint16_t*)(ws + WS_WIN);
  uint16_t* w_mid   = (uint16_t*)(ws + WS_WMID);
  uint16_t* w_out   = (uint16_t*)(ws + WS_WOUT);
  uint16_t* w_short = (uint16_t*)(ws + WS_WSHORT);
  float* out = (float*)d_out;

  hipLaunchKernelGGL(k_mix_bias, dim3(16), dim3(256), 0, stream,
                     lat, w_dyna, b_dyna, b_in_mix, b_mid_mix, b_out_mix,
                     b_short_mix, ws_mix, ws_bias);
  hipLaunchKernelGGL(k_weights, dim3(192), dim3(256), 0, stream,
                     k_in_mix, k_mid_mix, k_out_mix, k_short_mix, ws_mix,
                     w_in, w_mid, w_out, w_short);
  hipLaunchKernelGGL(k_main, dim3(1024), dim3(256), 0, stream,
                     x, ws_bias, w_in, w_mid, w_out, w_short, out);
}

// Round 9
// 192.493 us; speedup vs baseline: 1.0184x; 1.0184x over previous
//
#include <hip/hip_runtime.h>
#include <stdint.h>

#define B_    16
#define FIN   256
#define FOUT  256
#define FH2   256
#define NMIX  8
#define LAT   512
#define HW    4096
#define MT    64

typedef short bf16x8 __attribute__((ext_vector_type(8)));
typedef float f32x4  __attribute__((ext_vector_type(4)));

// workspace layout (bytes) -- v7 layout (16x16x32 fragment packing)
#define WS_MIX    0           // [16][8] f32
#define WS_BIAS   1024        // [4][16][256] f32 : in, mid, out, short
#define WS_WIN    131072      // [16][65536] bf16, fragment-packed
#define WS_WMID   2228224     // [16][131072] bf16, fragment-packed (sin/cos interleaved k')
#define WS_WOUT   6422528     // [16][131072] bf16, fragment-packed
#define WS_WSHORT 10616832    // [16][65536] bf16, fragment-packed

// RNE f32->bf16, bit-twiddle (PROVEN bits; round-6 lesson: v_cvt_pk_bf16_f32 is
// NOT bit-identical -- do not substitute).
__device__ __forceinline__ uint16_t f2bf(float f) {
  uint32_t u = __builtin_bit_cast(uint32_t, f);
  u += 0x7fffu + ((u >> 16) & 1u);
  return (uint16_t)(u >> 16);
}
__device__ __forceinline__ uint32_t pack2(float lo, float hi) {
  return (uint32_t)f2bf(lo) | ((uint32_t)f2bf(hi) << 16);
}
// one range reduction for both sin and cos (f32 approx, pre-bf16-quantization)
__device__ __forceinline__ uint32_t packsc(float a) {
  float s, c;
  __sincosf(a, &s, &c);
  return pack2(s, c);
}

#define MFMA(a, b, c) __builtin_amdgcn_mfma_f32_16x16x32_bf16(a, b, c, 0, 0, 0)

// ---------------- kernel A: mix + biases (one block per sample) ----------------
__global__ void k_mix_bias(const float* __restrict__ lat,
                           const float* __restrict__ w_dyna,
                           const float* __restrict__ b_dyna,
                           const float* __restrict__ b_in_mix,
                           const float* __restrict__ b_mid_mix,
                           const float* __restrict__ b_out_mix,
                           const float* __restrict__ b_short_mix,
                           float* __restrict__ ws_mix,
                           float* __restrict__ ws_bias) {
  __shared__ float smix[NMIX];
  const int t = threadIdx.x;
  const int lane = t & 63, wv = t >> 6;
  const int b = blockIdx.x;
#pragma unroll
  for (int d2 = 0; d2 < 2; d2++) {
    int m = wv * 2 + d2;
    float s = 0.f;
#pragma unroll
    for (int j = 0; j < 8; j++)
      s += lat[b * LAT + j * 64 + lane] * w_dyna[m * LAT + j * 64 + lane];
#pragma unroll
    for (int off = 32; off; off >>= 1) s += __shfl_xor(s, off);
    if (lane == 0) {
      float v = s + b_dyna[m];
      ws_mix[b * NMIX + m] = v;
      smix[m] = v;
    }
  }
  __syncthreads();
  const float* banks[4] = {b_in_mix, b_mid_mix, b_out_mix, b_short_mix};
  for (int pos = t; pos < 1024; pos += 256) {
    int bank = pos >> 8, ch = pos & 255;
    const float* bp = banks[bank];
    float a = 0.f;
#pragma unroll
    for (int m = 0; m < NMIX; m++) a += smix[m] * bp[m * 256 + ch];
    ws_bias[(bank * B_ + b) * 256 + ch] = a;
  }
}

// ---------------- kernel B: mixed per-sample bf16 weights, FRAGMENT-PACKED ----
// (v7 version -- passed, bit-identical packed layout)
__global__ void k_weights(const float* __restrict__ k_in_mix,
                          const float* __restrict__ k_mid_mix,
                          const float* __restrict__ k_out_mix,
                          const float* __restrict__ k_short_mix,
                          const float* __restrict__ ws_mix,
                          uint16_t* __restrict__ w_in,
                          uint16_t* __restrict__ w_mid,
                          uint16_t* __restrict__ w_out,
                          uint16_t* __restrict__ w_short) {
  __shared__ float smix[B_ * NMIX];
  const int t = threadIdx.x;
  if (t < B_ * NMIX) smix[t] = ws_mix[t];
  __syncthreads();
  const int e8 = (blockIdx.x * 256 + t) * 8;  // 8-aligned packed position
  const float* srcA;
  uint16_t* dst;
  int sstride, dstride;
  bool ileave;  // block-uniform
  if (e8 < 65536) {                       // w_in, KT=8
    int e = e8;
    int lane = (e >> 3) & 63, ots = (e >> 9) & 3, kt = (e >> 11) & 7, wv = e >> 14;
    int row = wv * 64 + ots * 16 + (lane & 15);
    int k0 = kt * 32 + (lane >> 4) * 8;
    srcA = k_in_mix + row * 256 + k0; sstride = 65536; ileave = false;
    dst = w_in + e;                   dstride = 65536;
  } else if (e8 < 196608) {               // w_mid, KT=16, sin/cos interleave
    int e = e8 - 65536;
    int lane = (e >> 3) & 63, ots = (e >> 9) & 3, kt = (e >> 11) & 15, wv = e >> 15;
    int row = wv * 64 + ots * 16 + (lane & 15);
    int kp0 = kt * 32 + (lane >> 4) * 8;       // 8-aligned -> i0 = kp0/2, 4-aligned
    srcA = k_mid_mix + row * 512 + (kp0 >> 1); sstride = 131072; ileave = true;
    dst = w_mid + e;                           dstride = 131072;
  } else if (e8 < 327680) {               // w_out, KT=16, interleave
    int e = e8 - 196608;
    int lane = (e >> 3) & 63, ots = (e >> 9) & 3, kt = (e >> 11) & 15, wv = e >> 15;
    int row = wv * 64 + ots * 16 + (lane & 15);
    int kp0 = kt * 32 + (lane >> 4) * 8;
    srcA = k_out_mix + row * 512 + (kp0 >> 1); sstride = 131072; ileave = true;
    dst = w_out + e;                           dstride = 131072;
  } else {                                // w_short, KT=8
    int e = e8 - 327680;
    int lane = (e >> 3) & 63, ots = (e >> 9) & 3, kt = (e >> 11) & 7, wv = e >> 14;
    int row = wv * 64 + ots * 16 + (lane & 15);
    int k0 = kt * 32 + (lane >> 4) * 8;
    srcA = k_short_mix + row * 256 + k0; sstride = 65536; ileave = false;
    dst = w_short + e;                   dstride = 65536;
  }
  // srcB offset: non-interleaved -> +4 (elements 4..7); interleaved -> +256 (cos half)
  const int boff = ileave ? 256 : 4;
  float4 va[NMIX], vb[NMIX];
#pragma unroll
  for (int m = 0; m < NMIX; m++) {
    va[m] = *(const float4*)(srcA + m * sstride);
    vb[m] = *(const float4*)(srcA + m * sstride + boff);
  }
  for (int b = 0; b < B_; b++) {
    float4 ra = make_float4(0.f, 0.f, 0.f, 0.f), rb = ra;
#pragma unroll
    for (int m = 0; m < NMIX; m++) {
      const float s = smix[b * NMIX + m];
      ra.x += s * va[m].x; ra.y += s * va[m].y; ra.z += s * va[m].z; ra.w += s * va[m].w;
      rb.x += s * vb[m].x; rb.y += s * vb[m].y; rb.z += s * vb[m].z; rb.w += s * vb[m].w;
    }
    int4 pkt;
    if (ileave) {  // out order: a0,b0,a1,b1,a2,b2,a3,b3  (sin/cos interleave)
      pkt = make_int4((int)pack2(ra.x, rb.x), (int)pack2(ra.y, rb.y),
                      (int)pack2(ra.z, rb.z), (int)pack2(ra.w, rb.w));
    } else {       // out order: a0,a1,a2,a3,b0,b1,b2,b3
      pkt = make_int4((int)pack2(ra.x, ra.y), (int)pack2(ra.z, ra.w),
                      (int)pack2(rb.x, rb.y), (int)pack2(rb.z, rb.w));
    }
    *(int4*)(dst + (size_t)b * dstride) = pkt;
  }
}

// ---------------- main fused kernel (v9 = v7 + __sincosf epilogues) ----
// v8 (32x32x16) regressed (77.5 vs 74.1): longer per-MFMA occupancy with
// fewer independent MFMAs starved issue at 2 waves/SIMD. Reverted to 16x16x32.
// Change vs v7: complex_wave epilogues use __sincosf (one range reduction per
// sin/cos pair; 512 trig calls -> 256). f2bf bits untouched.
__launch_bounds__(256, 2)
__global__ void k_main(const float* __restrict__ x,
                       const float* __restrict__ ws_bias,
                       const uint16_t* __restrict__ w_in,
                       const uint16_t* __restrict__ w_mid,
                       const uint16_t* __restrict__ w_out,
                       const uint16_t* __restrict__ w_short,
                       float* __restrict__ out) {
  __shared__ int4 smem4[65536 / 16];
  char* lds = (char*)smem4;
  char* Xs = lds;            // 32768 bytes: [64 pos][256 ch] bf16, chunk-xor swz
  char* H1 = lds;            // 65536 bytes: [64 pos][512 ch] bf16 (after phase A)

  const int t = threadIdx.x;
  const int lane = t & 63;
  const int wv = t >> 6;     // 0..3
  const int q = lane >> 4;
  const int n = lane & 15;
  const int b = blockIdx.x & 15;
  const int p0 = (blockIdx.x >> 4) * MT;

  const float* xb = x + (size_t)b * FIN * HW + p0;
  const int xpos = t & 63;   // position this thread stages

  // ---- stage FULL X tile: 64 scalar loads/thread, one burst, one drain ----
  {
    float xr[8][8];
#pragma unroll
    for (int u = 0; u < 8; u++) {
      const int cg = wv * 8 + u;  // 8-channel group 0..31
#pragma unroll
      for (int e = 0; e < 8; e++)
        xr[u][e] = xb[(size_t)(cg * 8 + e) * HW + xpos];
    }
#pragma unroll
    for (int u = 0; u < 8; u++) {
      const int cg = wv * 8 + u;
      *(int4*)(Xs + xpos * 512 + ((cg ^ (xpos & 7)) * 16)) = make_int4(
          (int)pack2(xr[u][0], xr[u][1]), (int)pack2(xr[u][2], xr[u][3]),
          (int)pack2(xr[u][4], xr[u][5]), (int)pack2(xr[u][6], xr[u][7]));
    }
  }

  // ---- phase A accumulator init: h = b_in, s = b_short ----
  f32x4 acc_h[4][4], acc_s[4][4];
#pragma unroll
  for (int ots = 0; ots < 4; ots++) {
    const int o = wv * 64 + ots * 16 + q * 4;
    const float4 vi = *(const float4*)&ws_bias[(0 * B_ + b) * 256 + o];
    const float4 vs = *(const float4*)&ws_bias[(3 * B_ + b) * 256 + o];
    f32x4 ah, asv;
    ah[0] = vi.x; ah[1] = vi.y; ah[2] = vi.z; ah[3] = vi.w;
    asv[0] = vs.x; asv[1] = vs.y; asv[2] = vs.z; asv[3] = vs.w;
#pragma unroll
    for (int pt = 0; pt < 4; pt++) { acc_h[ots][pt] = ah; acc_s[ots][pt] = asv; }
  }

  // phase-A weight prefetch: kt=0 -> buf0, kt=1 -> buf1, before the barrier
  const uint16_t* Wi = w_in + (size_t)b * 65536 + wv * 16384 + lane * 8;
  const uint16_t* Ws = w_short + (size_t)b * 65536 + wv * 16384 + lane * 8;
  bf16x8 ai[2][4], asf[2][4];
#pragma unroll
  for (int ots = 0; ots < 4; ots++) {
    ai[0][ots] = *(const bf16x8*)(Wi + 0 * 2048 + ots * 512);
    asf[0][ots] = *(const bf16x8*)(Ws + 0 * 2048 + ots * 512);
    ai[1][ots] = *(const bf16x8*)(Wi + 1 * 2048 + ots * 512);
    asf[1][ots] = *(const bf16x8*)(Ws + 1 * 2048 + ots * 512);
  }
  __syncthreads();  // bar1: X staged (single vmcnt drain for all of X)

  // ---- phase A: h1 = K_in @ X + b_in ; short = K_short @ X + b_short ----
  // Barrier-free; weight loads for kt+2 issued AFTER cluster kt (dist 2).
#pragma unroll
  for (int kt = 0; kt < 8; kt++) {
    bf16x8 bf[4];
#pragma unroll
    for (int pt = 0; pt < 4; pt++) {
      const int p = pt * 16 + n;
      bf[pt] = *(const bf16x8*)(Xs + p * 512 + (((kt * 4 + q) ^ (p & 7)) * 16));
    }
    __builtin_amdgcn_s_setprio(1);
#pragma unroll
    for (int ots = 0; ots < 4; ots++) {
#pragma unroll
      for (int pt = 0; pt < 4; pt++) {
        acc_h[ots][pt] = MFMA(ai[kt & 1][ots], bf[pt], acc_h[ots][pt]);
        acc_s[ots][pt] = MFMA(asf[kt & 1][ots], bf[pt], acc_s[ots][pt]);
      }
    }
    __builtin_amdgcn_s_setprio(0);
    if (kt < 6) {  // refill the buffer just consumed with kt+2
#pragma unroll
      for (int ots = 0; ots < 4; ots++) {
        ai[kt & 1][ots] = *(const bf16x8*)(Wi + (kt + 2) * 2048 + ots * 512);
        asf[kt & 1][ots] = *(const bf16x8*)(Ws + (kt + 2) * 2048 + ots * 512);
      }
    }
  }
  __syncthreads();  // bar2: all X reads done before H1 overwrites the region

  // ---- complex_wave(h1) -> H1 (k' = 2*o + {0:sin,1:cos}, ctile-xor swizzle) ----
#pragma unroll
  for (int ots = 0; ots < 4; ots++) {
    const int ctile = (wv * 4 + ots) * 4 + q;
#pragma unroll
    for (int pt = 0; pt < 4; pt++) {
      const int p = pt * 16 + n;
      *(int4*)(H1 + p * 1024 + ((ctile ^ (p & 7)) * 16)) = make_int4(
          (int)packsc(acc_h[ots][pt][0]), (int)packsc(acc_h[ots][pt][1]),
          (int)packsc(acc_h[ots][pt][2]), (int)packsc(acc_h[ots][pt][3]));
    }
  }

  // phase-B prologue: bias init + 3 weight buffers (kt 0,1,2), before barrier
  const uint16_t* Wm = w_mid + (size_t)b * 131072 + wv * 32768 + lane * 8;
  bf16x8 am[3][4];
#pragma unroll
  for (int ots = 0; ots < 4; ots++) {
    am[0][ots] = *(const bf16x8*)(Wm + 0 * 2048 + ots * 512);
    am[1][ots] = *(const bf16x8*)(Wm + 1 * 2048 + ots * 512);
    am[2][ots] = *(const bf16x8*)(Wm + 2 * 2048 + ots * 512);
  }
  f32x4 acc2[4][4];
#pragma unroll
  for (int ots = 0; ots < 4; ots++) {
    const int o = wv * 64 + ots * 16 + q * 4;
    const float4 v = *(const float4*)&ws_bias[(1 * B_ + b) * 256 + o];
    f32x4 a2;
    a2[0] = v.x; a2[1] = v.y; a2[2] = v.z; a2[3] = v.w;
#pragma unroll
    for (int pt = 0; pt < 4; pt++) acc2[ots][pt] = a2;
  }
  __syncthreads();  // bar3: H1 writes visible to all waves

  // ---- phase B: h2 = K_mid(perm) @ H1c + b_mid ----
  // ds ping-pong (kt+1 fragments before cluster kt); weight loads for kt+3
  // issued AFTER cluster kt into the just-freed buffer (distance 3).
  {
    bf16x8 bfP[2][4];
#pragma unroll
    for (int pt = 0; pt < 4; pt++) {
      const int p = pt * 16 + n;
      bfP[0][pt] = *(const bf16x8*)(H1 + p * 1024 + ((q ^ (p & 7)) * 16));
    }
#pragma unroll
    for (int kt = 0; kt < 16; kt++) {
      if (kt < 15) {
#pragma unroll
        for (int pt = 0; pt < 4; pt++) {
          const int p = pt * 16 + n;
          bfP[(kt + 1) & 1][pt] =
              *(const bf16x8*)(H1 + p * 1024 + ((((kt + 1) * 4 + q) ^ (p & 7)) * 16));
        }
      }
      __builtin_amdgcn_s_setprio(1);
#pragma unroll
      for (int ots = 0; ots < 4; ots++)
#pragma unroll
        for (int pt = 0; pt < 4; pt++)
          acc2[ots][pt] = MFMA(am[kt % 3][ots], bfP[kt & 1][pt], acc2[ots][pt]);
      __builtin_amdgcn_s_setprio(0);
      if (kt < 13) {
#pragma unroll
        for (int ots = 0; ots < 4; ots++)
          am[kt % 3][ots] = *(const bf16x8*)(Wm + (kt + 3) * 2048 + ots * 512);
      }
    }
  }
  __syncthreads();  // bar4: all H1 reads done before overwrite

  // ---- complex_wave(h2) -> H2 (overlays H1 region) ----
#pragma unroll
  for (int ots = 0; ots < 4; ots++) {
    const int ctile = (wv * 4 + ots) * 4 + q;
#pragma unroll
    for (int pt = 0; pt < 4; pt++) {
      const int p = pt * 16 + n;
      *(int4*)(H1 + p * 1024 + ((ctile ^ (p & 7)) * 16)) = make_int4(
          (int)packsc(acc2[ots][pt][0]), (int)packsc(acc2[ots][pt][1]),
          (int)packsc(acc2[ots][pt][2]), (int)packsc(acc2[ots][pt][3]));
    }
  }

  // phase-C prologue: acc3 = short + b_out (in place in acc_s) + 3 weight bufs
  const uint16_t* Wo = w_out + (size_t)b * 131072 + wv * 32768 + lane * 8;
  bf16x8 ao[3][4];
#pragma unroll
  for (int ots = 0; ots < 4; ots++) {
    ao[0][ots] = *(const bf16x8*)(Wo + 0 * 2048 + ots * 512);
    ao[1][ots] = *(const bf16x8*)(Wo + 1 * 2048 + ots * 512);
    ao[2][ots] = *(const bf16x8*)(Wo + 2 * 2048 + ots * 512);
  }
#pragma unroll
  for (int ots = 0; ots < 4; ots++) {
    const int o = wv * 64 + ots * 16 + q * 4;
    const float4 v = *(const float4*)&ws_bias[(2 * B_ + b) * 256 + o];
#pragma unroll
    for (int pt = 0; pt < 4; pt++) {
      acc_s[ots][pt][0] += v.x; acc_s[ots][pt][1] += v.y;
      acc_s[ots][pt][2] += v.z; acc_s[ots][pt][3] += v.w;
    }
  }
  __syncthreads();  // bar5: H2 writes visible

  // ---- phase C: out = K_out(perm) @ H2c + b_out + short ----
  {
    bf16x8 bfP[2][4];
#pragma unroll
    for (int pt = 0; pt < 4; pt++) {
      const int p = pt * 16 + n;
      bfP[0][pt] = *(const bf16x8*)(H1 + p * 1024 + ((q ^ (p & 7)) * 16));
    }
#pragma unroll
    for (int kt = 0; kt < 16; kt++) {
      if (kt < 15) {
#pragma unroll
        for (int pt = 0; pt < 4; pt++) {
          const int p = pt * 16 + n;
          bfP[(kt + 1) & 1][pt] =
              *(const bf16x8*)(H1 + p * 1024 + ((((kt + 1) * 4 + q) ^ (p & 7)) * 16));
        }
      }
      __builtin_amdgcn_s_setprio(1);
#pragma unroll
      for (int ots = 0; ots < 4; ots++)
#pragma unroll
        for (int pt = 0; pt < 4; pt++)
          acc_s[ots][pt] = MFMA(ao[kt % 3][ots], bfP[kt & 1][pt], acc_s[ots][pt]);
      __builtin_amdgcn_s_setprio(0);
      if (kt < 13) {
#pragma unroll
        for (int ots = 0; ots < 4; ots++)
          ao[kt % 3][ots] = *(const bf16x8*)(Wo + (kt + 3) * 2048 + ots * 512);
      }
    }
  }

  // ---- store ----
  {
    float* ob = out + (size_t)b * FOUT * HW + p0;
#pragma unroll
    for (int ots = 0; ots < 4; ots++) {
#pragma unroll
      for (int pt = 0; pt < 4; pt++) {
#pragma unroll
        for (int r = 0; r < 4; r++) {
          const int o = wv * 64 + ots * 16 + q * 4 + r;
          ob[(size_t)o * HW + pt * 16 + n] = acc_s[ots][pt][r];
        }
      }
    }
  }
}

extern "C" void kernel_launch(void* const* d_in, const int* in_sizes, int n_in,
                              void* d_out, int out_size, void* d_ws, size_t ws_size,
                              hipStream_t stream) {
  const float* x           = (const float*)d_in[0];
  const float* lat         = (const float*)d_in[1];
  const float* k_in_mix    = (const float*)d_in[2];
  const float* k_mid_mix   = (const float*)d_in[3];
  const float* k_out_mix   = (const float*)d_in[4];
  const float* k_short_mix = (const float*)d_in[5];
  const float* b_in_mix    = (const float*)d_in[6];
  const float* b_mid_mix   = (const float*)d_in[7];
  const float* b_out_mix   = (const float*)d_in[8];
  const float* b_short_mix = (const float*)d_in[9];
  const float* w_dyna      = (const float*)d_in[10];
  const float* b_dyna      = (const float*)d_in[11];

  char* ws = (char*)d_ws;
  float*    ws_mix  = (float*)(ws + WS_MIX);
  float*    ws_bias = (float*)(ws + WS_BIAS);
  uint16_t* w_in    = (uint16_t*)(ws + WS_WIN);
  uint16_t* w_mid   = (uint16_t*)(ws + WS_WMID);
  uint16_t* w_out   = (uint16_t*)(ws + WS_WOUT);
  uint16_t* w_short = (uint16_t*)(ws + WS_WSHORT);
  float* out = (float*)d_out;

  hipLaunchKernelGGL(k_mix_bias, dim3(16), dim3(256), 0, stream,
                     lat, w_dyna, b_dyna, b_in_mix, b_mid_mix, b_out_mix,
                     b_short_mix, ws_mix, ws_bias);
  hipLaunchKernelGGL(k_weights, dim3(192), dim3(256), 0, stream,
                     k_in_mix, k_mid_mix, k_out_mix, k_short_mix, ws_mix,
                     w_in, w_mid, w_out, w_short);
  hipLaunchKernelGGL(k_main, dim3(1024), dim3(256), 0, stream,
                     x, ws_bias, w_in, w_mid, w_out, w_short, out);
}